// Round 1
// baseline (2969.749 us; speedup 1.0000x reference)
//
#include <hip/hip_runtime.h>

#define N 8192
#define EPS 1e-5f

// ---------------------------------------------------------------------------
// ws layout:
//   [0]      double acc
//   [8]      unsigned counter       (edge count)
//   [12]     unsigned overflow      (edge list overflow flag)
//   [16]     float    deg[N]        (32 KB)
//   [16+4N]  unsigned edges[cap]    (packed (row<<16)|col, row<=col)
// ---------------------------------------------------------------------------

__global__ void k_init(float* __restrict__ deg, double* __restrict__ acc,
                       unsigned* __restrict__ counter, unsigned* __restrict__ overflow) {
    int t = blockIdx.x * blockDim.x + threadIdx.x;
    if (t == 0) { *acc = 0.0; *counter = 0u; *overflow = 0u; }
    for (int i = t; i < N; i += gridDim.x * blockDim.x) deg[i] = 0.f;
}

// Pass 1: read upper triangle once. Tiles of 128 rows x 256 cols.
// Produces deg[] (row-part + symmetric col-part) and packed edge list.
#define TR 128
#define TC 256
__global__ __launch_bounds__(256) void k_pass1(const float* __restrict__ g,
                                               const unsigned cap,
                                               float* __restrict__ deg,
                                               unsigned* __restrict__ counter,
                                               unsigned* __restrict__ overflow,
                                               unsigned* __restrict__ edges) {
    const int bi = blockIdx.x >> 5;   // 64 row-tiles
    const int bj = blockIdx.x & 31;   // 32 col-tiles
    const int r0 = bi * TR;
    const int c0 = bj * TC;
    if (c0 + TC - 1 < r0) return;     // tile entirely below diagonal

    const int wave = threadIdx.x >> 6;
    const int lane = threadIdx.x & 63;
    const int c = c0 + lane * 4;      // 64 lanes * float4 = 256 cols

    float ca0 = 0.f, ca1 = 0.f, ca2 = 0.f, ca3 = 0.f;  // per-column (c>row) accum
    const int rbeg = wave * 32;
    for (int r = rbeg; r < rbeg + 32; ++r) {
        const int gr = r0 + r;
        const float4 v = *reinterpret_cast<const float4*>(g + (size_t)gr * N + c);
        // row-part mask: col >= row (diagonal counted once, in row part)
        const float m0 = (c + 0 >= gr) ? v.x : 0.f;
        const float m1 = (c + 1 >= gr) ? v.y : 0.f;
        const float m2 = (c + 2 >= gr) ? v.z : 0.f;
        const float m3 = (c + 3 >= gr) ? v.w : 0.f;
        float rs = (m0 + m1) + (m2 + m3);
        #pragma unroll
        for (int off = 32; off; off >>= 1) rs += __shfl_xor(rs, off);
        if (lane == 0 && rs != 0.f) atomicAdd(&deg[gr], rs);
        // col-part mask: col > row (strict; symmetric counterpart g[j][i])
        ca0 += (c + 0 > gr) ? v.x : 0.f;
        ca1 += (c + 1 > gr) ? v.y : 0.f;
        ca2 += (c + 2 > gr) ? v.z : 0.f;
        ca3 += (c + 3 > gr) ? v.w : 0.f;
        // edge compaction (m* != 0 <=> in-triangle edge; values are exactly 0/1)
        if (m0 != 0.f) { unsigned x = atomicAdd(counter, 1u); if (x < cap) edges[x] = ((unsigned)gr << 16) | (unsigned)(c + 0); else *overflow = 1u; }
        if (m1 != 0.f) { unsigned x = atomicAdd(counter, 1u); if (x < cap) edges[x] = ((unsigned)gr << 16) | (unsigned)(c + 1); else *overflow = 1u; }
        if (m2 != 0.f) { unsigned x = atomicAdd(counter, 1u); if (x < cap) edges[x] = ((unsigned)gr << 16) | (unsigned)(c + 2); else *overflow = 1u; }
        if (m3 != 0.f) { unsigned x = atomicAdd(counter, 1u); if (x < cap) edges[x] = ((unsigned)gr << 16) | (unsigned)(c + 3); else *overflow = 1u; }
    }
    if (ca0 != 0.f) atomicAdd(&deg[c + 0], ca0);
    if (ca1 != 0.f) atomicAdd(&deg[c + 1], ca1);
    if (ca2 != 0.f) atomicAdd(&deg[c + 2], ca2);
    if (ca3 != 0.f) atomicAdd(&deg[c + 3], ca3);
}

// S0: dense sum over i<=j of log(1 - p(deg_i,deg_j) + eps). No graph reads.
__global__ __launch_bounds__(256) void k_dense(const float* __restrict__ deg,
                                               const float* __restrict__ params,
                                               const unsigned* __restrict__ overflow,
                                               double* __restrict__ acc) {
    if (*overflow) return;   // fallback kernel handles everything instead
    const int i = blockIdx.x;
    const float alpha = params[0], beta = params[1], sigma = params[2];
    const float base = fmaf(alpha, deg[i], sigma);
    float local = 0.f;
    for (int j = i + (int)threadIdx.x; j < N; j += 256) {
        const float s = fmaf(beta, deg[j], base);
        const float p = __fdividef(1.f, 1.f + __expf(s));
        local += __logf(1.f - p + EPS);
    }
    #pragma unroll
    for (int off = 32; off; off >>= 1) local += __shfl_xor(local, off);
    __shared__ float wsum[4];
    const int wave = threadIdx.x >> 6, lane = threadIdx.x & 63;
    if (lane == 0) wsum[wave] = local;
    __syncthreads();
    if (threadIdx.x == 0) {
        const float t = (wsum[0] + wsum[1]) + (wsum[2] + wsum[3]);
        atomicAdd(acc, (double)t);
    }
}

// S1: per-edge correction log(p+eps) - log(1-p+eps) over the compacted list.
__global__ __launch_bounds__(256) void k_edges(const float* __restrict__ deg,
                                               const float* __restrict__ params,
                                               const unsigned* __restrict__ edges,
                                               const unsigned* __restrict__ counter,
                                               const unsigned* __restrict__ overflow,
                                               const unsigned cap,
                                               double* __restrict__ acc) {
    if (*overflow) return;
    const unsigned cnt = *counter;
    const unsigned n = cnt < cap ? cnt : cap;
    const float alpha = params[0], beta = params[1], sigma = params[2];
    float local = 0.f;
    for (unsigned t = blockIdx.x * 256u + threadIdx.x; t < n; t += gridDim.x * 256u) {
        const unsigned e = edges[t];
        const float di = deg[e >> 16];
        const float dj = deg[e & 0xffffu];
        const float s = fmaf(alpha, di, fmaf(beta, dj, sigma));
        const float p = __fdividef(1.f, 1.f + __expf(s));
        local += __logf(p + EPS) - __logf(1.f - p + EPS);
    }
    #pragma unroll
    for (int off = 32; off; off >>= 1) local += __shfl_xor(local, off);
    __shared__ float wsum[4];
    const int wave = threadIdx.x >> 6, lane = threadIdx.x & 63;
    if (lane == 0) wsum[wave] = local;
    __syncthreads();
    if (threadIdx.x == 0) {
        const float t = (wsum[0] + wsum[1]) + (wsum[2] + wsum[3]);
        atomicAdd(acc, (double)t);
    }
}

// Fallback (only if edge list overflowed ws): recompute full upper-tri sum
// directly from the graph. Early-exits (per block) when not needed.
__global__ __launch_bounds__(256) void k_fallback(const float* __restrict__ g,
                                                  const float* __restrict__ deg,
                                                  const float* __restrict__ params,
                                                  const unsigned* __restrict__ overflow,
                                                  double* __restrict__ acc) {
    if (!*overflow) return;
    const int i = blockIdx.x;
    const float alpha = params[0], beta = params[1], sigma = params[2];
    const float base = fmaf(alpha, deg[i], sigma);
    double local = 0.0;
    for (int j = i + (int)threadIdx.x; j < N; j += 256) {
        const float s = fmaf(beta, deg[j], base);
        const float p = __fdividef(1.f, 1.f + __expf(s));
        const float gv = g[(size_t)i * N + j];
        local += (gv != 0.f) ? __logf(p + EPS) : __logf(1.f - p + EPS);
    }
    #pragma unroll
    for (int off = 32; off; off >>= 1) local += __shfl_xor(local, off);
    __shared__ double wsum[4];
    const int wave = threadIdx.x >> 6, lane = threadIdx.x & 63;
    if (lane == 0) wsum[wave] = local;
    __syncthreads();
    if (threadIdx.x == 0) {
        atomicAdd(acc, (wsum[0] + wsum[1]) + (wsum[2] + wsum[3]));
    }
}

__global__ void k_final(const double* __restrict__ acc, float* __restrict__ out) {
    if (threadIdx.x == 0 && blockIdx.x == 0) out[0] = (float)(-*acc);
}

extern "C" void kernel_launch(void* const* d_in, const int* in_sizes, int n_in,
                              void* d_out, int out_size, void* d_ws, size_t ws_size,
                              hipStream_t stream) {
    const float* params = (const float*)d_in[0];   // [alpha, beta, sigma]
    const float* graph  = (const float*)d_in[1];   // [N, N] fp32 0/1
    float* out = (float*)d_out;

    char* ws = (char*)d_ws;
    double*   acc      = (double*)(ws + 0);
    unsigned* counter  = (unsigned*)(ws + 8);
    unsigned* overflow = (unsigned*)(ws + 12);
    float*    deg      = (float*)(ws + 16);
    unsigned* edges    = (unsigned*)(ws + 16 + (size_t)N * 4);
    const size_t head  = 16 + (size_t)N * 4;
    const unsigned cap = (ws_size > head) ? (unsigned)((ws_size - head) / 4) : 0u;

    k_init<<<32, 256, 0, stream>>>(deg, acc, counter, overflow);
    k_pass1<<<64 * 32, 256, 0, stream>>>(graph, cap, deg, counter, overflow, edges);
    k_dense<<<N, 256, 0, stream>>>(deg, params, overflow, acc);
    k_edges<<<256, 256, 0, stream>>>(deg, params, edges, counter, overflow, cap, acc);
    k_fallback<<<N, 256, 0, stream>>>(graph, deg, params, overflow, acc);
    k_final<<<1, 1, 0, stream>>>(acc, out);
}

// Round 2
// 123.486 us; speedup vs baseline: 24.0492x; 24.0492x over previous
//
#include <hip/hip_runtime.h>

#define N 8192
#define EPS 1e-5f

// ---------------------------------------------------------------------------
// ws layout:
//   [0]      double acc
//   [8]      unsigned counter       (edge count)
//   [12]     unsigned overflow      (edge list overflow flag)
//   [16]     float    deg[N]        (32 KB)
//   [16+4N]  unsigned edges[cap]    (packed (row<<16)|col, row<=col)
// ---------------------------------------------------------------------------

__global__ void k_init(float* __restrict__ deg, double* __restrict__ acc,
                       unsigned* __restrict__ counter, unsigned* __restrict__ overflow) {
    int t = blockIdx.x * blockDim.x + threadIdx.x;
    if (t == 0) { *acc = 0.0; *counter = 0u; *overflow = 0u; }
    for (int i = t; i < N; i += gridDim.x * blockDim.x) deg[i] = 0.f;
}

// Pass 1: read upper triangle once. Tiles of TR=128 rows x TC=256 cols.
// Edge compaction via per-wave LDS buffers; ONE global counter atomic per
// block (was: one per edge -> 335K serialized RMWs = 2.8 ms).
#define TR 128
#define TC 256
#define CAPW 512   // per-wave LDS edge buffer entries (>= 2*256 headroom rule)

__global__ __launch_bounds__(256) void k_pass1(const float* __restrict__ g,
                                               const unsigned cap,
                                               float* __restrict__ deg,
                                               unsigned* __restrict__ counter,
                                               unsigned* __restrict__ overflow,
                                               unsigned* __restrict__ edges) {
    const int bi = blockIdx.x >> 5;   // 64 row-tiles
    const int bj = blockIdx.x & 31;   // 32 col-tiles
    if (bi > 2 * bj + 1) return;      // tile entirely below diagonal
    const int r0 = bi * TR;
    const int c0 = bj * TC;

    __shared__ float    sdeg[TR];        // per-row sums (unique wave owner)
    __shared__ float    scol[TC];        // per-col sums (LDS atomics)
    __shared__ unsigned buf[4][CAPW];    // per-wave edge buffers
    __shared__ unsigned wcnt[4];
    __shared__ unsigned wbase[4];

    const int tid  = threadIdx.x;
    const int wave = tid >> 6;
    const int lane = tid & 63;

    if (tid < TR) sdeg[tid] = 0.f;
    scol[tid] = 0.f;
    if (tid < 4) wcnt[tid] = 0u;
    __syncthreads();

    const int c = c0 + lane * 4;
    float ca0 = 0.f, ca1 = 0.f, ca2 = 0.f, ca3 = 0.f;

    for (int k = 0; k < 32; ++k) {
        // emergency flush (wave-local, wave-synchronous): guarantee room for
        // the <=256 edges this wave can add in one row
        unsigned m = wcnt[wave];
        if (m > (unsigned)(CAPW - 256)) {
            unsigned base = 0;
            if (lane == 0) base = atomicAdd(counter, m);
            base = __shfl(base, 0);
            for (unsigned t = lane; t < m; t += 64) {
                unsigned idx = base + t;
                if (idx < cap) edges[idx] = buf[wave][t];
            }
            if (lane == 0) {
                if (base + m > cap) *overflow = 1u;
                wcnt[wave] = 0u;
            }
        }

        const int lr = wave * 32 + k;
        const int gr = r0 + lr;
        const float4 v = *reinterpret_cast<const float4*>(g + (size_t)gr * N + c);
        // row-part mask: col >= row (diagonal counted once, in row part)
        const float m0 = (c + 0 >= gr) ? v.x : 0.f;
        const float m1 = (c + 1 >= gr) ? v.y : 0.f;
        const float m2 = (c + 2 >= gr) ? v.z : 0.f;
        const float m3 = (c + 3 >= gr) ? v.w : 0.f;
        float rs = (m0 + m1) + (m2 + m3);
        #pragma unroll
        for (int off = 32; off; off >>= 1) rs += __shfl_xor(rs, off);
        if (lane == 0 && rs != 0.f) sdeg[lr] += rs;
        // col-part mask: col > row (strict; symmetric counterpart g[j][i])
        ca0 += (c + 0 > gr) ? v.x : 0.f;
        ca1 += (c + 1 > gr) ? v.y : 0.f;
        ca2 += (c + 2 > gr) ? v.z : 0.f;
        ca3 += (c + 3 > gr) ? v.w : 0.f;
        // edge compaction into per-wave LDS buffer (values exactly 0/1)
        if (m0 != 0.f) { unsigned s = atomicAdd(&wcnt[wave], 1u); if (s < CAPW) buf[wave][s] = ((unsigned)gr << 16) | (unsigned)(c + 0); }
        if (m1 != 0.f) { unsigned s = atomicAdd(&wcnt[wave], 1u); if (s < CAPW) buf[wave][s] = ((unsigned)gr << 16) | (unsigned)(c + 1); }
        if (m2 != 0.f) { unsigned s = atomicAdd(&wcnt[wave], 1u); if (s < CAPW) buf[wave][s] = ((unsigned)gr << 16) | (unsigned)(c + 2); }
        if (m3 != 0.f) { unsigned s = atomicAdd(&wcnt[wave], 1u); if (s < CAPW) buf[wave][s] = ((unsigned)gr << 16) | (unsigned)(c + 3); }
    }

    // column partials -> LDS (cross-wave: needs atomics; LDS atomics are fast)
    if (ca0 != 0.f) atomicAdd(&scol[lane * 4 + 0], ca0);
    if (ca1 != 0.f) atomicAdd(&scol[lane * 4 + 1], ca1);
    if (ca2 != 0.f) atomicAdd(&scol[lane * 4 + 2], ca2);
    if (ca3 != 0.f) atomicAdd(&scol[lane * 4 + 3], ca3);
    __syncthreads();

    // single global counter atomic for the whole block
    if (tid == 0) {
        unsigned tot = wcnt[0] + wcnt[1] + wcnt[2] + wcnt[3];
        unsigned b = tot ? atomicAdd(counter, tot) : 0u;
        for (int w = 0; w < 4; ++w) { wbase[w] = b; b += wcnt[w]; }
        if (b > cap) *overflow = 1u;
    }
    __syncthreads();
    {
        const unsigned m = wcnt[wave], b = wbase[wave];
        for (unsigned t = lane; t < m; t += 64) {
            unsigned idx = b + t;
            if (idx < cap) edges[idx] = buf[wave][t];
        }
    }
    // degree flushes (distributed addresses -> pipelined atomics)
    if (tid < TR) { float v = sdeg[tid]; if (v != 0.f) atomicAdd(&deg[r0 + tid], v); }
    { float v = scol[tid]; if (v != 0.f) atomicAdd(&deg[c0 + tid], v); }
}

// S0: dense sum over i<=j of log(1 - p(deg_i,deg_j) + eps). No graph reads.
// Balanced: block b handles rows b and N-1-b (exactly N+1 iters per block).
__global__ __launch_bounds__(256) void k_dense(const float* __restrict__ deg,
                                               const float* __restrict__ params,
                                               const unsigned* __restrict__ overflow,
                                               double* __restrict__ acc) {
    if (*overflow) return;   // fallback kernel handles everything instead
    const int r1 = blockIdx.x;
    const int r2 = N - 1 - r1;
    const float alpha = params[0], beta = params[1], sigma = params[2];
    const float base1 = fmaf(alpha, deg[r1], sigma);
    const float base2 = fmaf(alpha, deg[r2], sigma);
    float local = 0.f;
    for (int j = r1 + (int)threadIdx.x; j < N; j += 256) {
        const float s = fmaf(beta, deg[j], base1);
        const float p = __fdividef(1.f, 1.f + __expf(s));
        local += __logf(1.f - p + EPS);
    }
    for (int j = r2 + (int)threadIdx.x; j < N; j += 256) {
        const float s = fmaf(beta, deg[j], base2);
        const float p = __fdividef(1.f, 1.f + __expf(s));
        local += __logf(1.f - p + EPS);
    }
    #pragma unroll
    for (int off = 32; off; off >>= 1) local += __shfl_xor(local, off);
    __shared__ float wsum[4];
    const int wave = threadIdx.x >> 6, lane = threadIdx.x & 63;
    if (lane == 0) wsum[wave] = local;
    __syncthreads();
    if (threadIdx.x == 0) {
        const float t = (wsum[0] + wsum[1]) + (wsum[2] + wsum[3]);
        atomicAdd(acc, (double)t);
    }
}

// S1: per-edge correction log(p+eps) - log(1-p+eps) over the compacted list.
__global__ __launch_bounds__(256) void k_edges(const float* __restrict__ deg,
                                               const float* __restrict__ params,
                                               const unsigned* __restrict__ edges,
                                               const unsigned* __restrict__ counter,
                                               const unsigned* __restrict__ overflow,
                                               const unsigned cap,
                                               double* __restrict__ acc) {
    if (*overflow) return;
    const unsigned cnt = *counter;
    const unsigned n = cnt < cap ? cnt : cap;
    const float alpha = params[0], beta = params[1], sigma = params[2];
    float local = 0.f;
    for (unsigned t = blockIdx.x * 256u + threadIdx.x; t < n; t += gridDim.x * 256u) {
        const unsigned e = edges[t];
        const float di = deg[e >> 16];
        const float dj = deg[e & 0xffffu];
        const float s = fmaf(alpha, di, fmaf(beta, dj, sigma));
        const float p = __fdividef(1.f, 1.f + __expf(s));
        local += __logf(p + EPS) - __logf(1.f - p + EPS);
    }
    #pragma unroll
    for (int off = 32; off; off >>= 1) local += __shfl_xor(local, off);
    __shared__ float wsum[4];
    const int wave = threadIdx.x >> 6, lane = threadIdx.x & 63;
    if (lane == 0) wsum[wave] = local;
    __syncthreads();
    if (threadIdx.x == 0) {
        const float t = (wsum[0] + wsum[1]) + (wsum[2] + wsum[3]);
        atomicAdd(acc, (double)t);
    }
}

// Fallback (only if edge list overflowed ws): recompute full upper-tri sum
// directly from the graph. Early-exits (per block) when not needed.
__global__ __launch_bounds__(256) void k_fallback(const float* __restrict__ g,
                                                  const float* __restrict__ deg,
                                                  const float* __restrict__ params,
                                                  const unsigned* __restrict__ overflow,
                                                  double* __restrict__ acc) {
    if (!*overflow) return;
    const int i = blockIdx.x;
    const float alpha = params[0], beta = params[1], sigma = params[2];
    const float base = fmaf(alpha, deg[i], sigma);
    double local = 0.0;
    for (int j = i + (int)threadIdx.x; j < N; j += 256) {
        const float s = fmaf(beta, deg[j], base);
        const float p = __fdividef(1.f, 1.f + __expf(s));
        const float gv = g[(size_t)i * N + j];
        local += (gv != 0.f) ? __logf(p + EPS) : __logf(1.f - p + EPS);
    }
    #pragma unroll
    for (int off = 32; off; off >>= 1) local += __shfl_xor(local, off);
    __shared__ double wsum[4];
    const int wave = threadIdx.x >> 6, lane = threadIdx.x & 63;
    if (lane == 0) wsum[wave] = local;
    __syncthreads();
    if (threadIdx.x == 0) {
        atomicAdd(acc, (wsum[0] + wsum[1]) + (wsum[2] + wsum[3]));
    }
}

__global__ void k_final(const double* __restrict__ acc, float* __restrict__ out) {
    if (threadIdx.x == 0 && blockIdx.x == 0) out[0] = (float)(-*acc);
}

extern "C" void kernel_launch(void* const* d_in, const int* in_sizes, int n_in,
                              void* d_out, int out_size, void* d_ws, size_t ws_size,
                              hipStream_t stream) {
    const float* params = (const float*)d_in[0];   // [alpha, beta, sigma]
    const float* graph  = (const float*)d_in[1];   // [N, N] fp32 0/1
    float* out = (float*)d_out;

    char* ws = (char*)d_ws;
    double*   acc      = (double*)(ws + 0);
    unsigned* counter  = (unsigned*)(ws + 8);
    unsigned* overflow = (unsigned*)(ws + 12);
    float*    deg      = (float*)(ws + 16);
    unsigned* edges    = (unsigned*)(ws + 16 + (size_t)N * 4);
    const size_t head  = 16 + (size_t)N * 4;
    const unsigned cap = (ws_size > head) ? (unsigned)((ws_size - head) / 4) : 0u;

    k_init<<<32, 256, 0, stream>>>(deg, acc, counter, overflow);
    k_pass1<<<64 * 32, 256, 0, stream>>>(graph, cap, deg, counter, overflow, edges);
    k_dense<<<N / 2, 256, 0, stream>>>(deg, params, overflow, acc);
    k_edges<<<256, 256, 0, stream>>>(deg, params, edges, counter, overflow, cap, acc);
    k_fallback<<<N, 256, 0, stream>>>(graph, deg, params, overflow, acc);
    k_final<<<1, 1, 0, stream>>>(acc, out);
}

// Round 3
// 77.594 us; speedup vs baseline: 38.2727x; 1.5914x over previous
//
#include <hip/hip_runtime.h>

#define N 8192
#define EPS 1e-5f

#define TR 64        // rows per tile
#define TC 256       // cols per tile
#define NBJ 32       // N/TC col-tiles
#define NBI 128      // N/TR row-tiles
#define RPW 16       // rows per wave (4 waves/block)
#define SEG_W 4096   // worst-case edges per wave segment (RPW*TC)
#define CAPW 512     // LDS edge buffer entries per wave
#define NTILES 2112  // active upper-tri tiles
#define NDENSE 4096  // dense pair-blocks (N/2)
#define NFB 1024     // fallback blocks

// ws layout (bytes):
//   accv  [0,4096)        64 double slots, stride 8 doubles (one per cache line)
//   ovf   [4096]
//   deg   [4224, +32768)
//   cnt   [36992, +NTILES*4*4)
//   edges [70784, +NTILES*4*SEG_W*4)   total ~132 MB (ws is ~1 GB)
static const size_t OFF_ACC = 0;
static const size_t OFF_OVF = 4096;
static const size_t OFF_DEG = 4224;
static const size_t OFF_CNT = OFF_DEG + (size_t)N * 4;
static const size_t OFF_EDG = OFF_CNT + (size_t)NTILES * 4 * 4;
static const size_t WS_NEED = OFF_EDG + (size_t)NTILES * 4 * SEG_W * 4;

__device__ __forceinline__ unsigned mbcnt64(unsigned long long m) {
    return __builtin_amdgcn_mbcnt_hi((unsigned)(m >> 32),
           __builtin_amdgcn_mbcnt_lo((unsigned)m, 0u));
}

__global__ void k_init(float* __restrict__ deg, double* __restrict__ accv,
                       unsigned* __restrict__ ovf, const int segmode) {
    const int t = blockIdx.x * 256 + threadIdx.x;
    if (t < 512) accv[t] = 0.0;
    if (t == 512) *ovf = segmode ? 0u : 1u;
    if (t < N) deg[t] = 0.f;
}

// Pass 1: stream the upper triangle once. Row sums via scalar popc of
// ballots (values are exactly 0/1); edge compaction via ballot-rank into
// per-wave LDS buffer, flushed to a deterministic per-(tile,wave) global
// segment. No shuffles, no LDS atomics in the hot loop, no global counter.
__global__ __launch_bounds__(256) void k_pass1(const float* __restrict__ g,
        float* __restrict__ deg, unsigned* __restrict__ cnt,
        unsigned* __restrict__ edges, const int segmode) {
    const int bj = (int)blockIdx.x & (NBJ - 1);
    const int bi = (int)blockIdx.x >> 5;
    if (bi > 4 * bj + 3) return;                 // tile fully below diagonal
    const int r0 = bi * TR, c0 = bj * TC;
    const int wave = threadIdx.x >> 6, lane = threadIdx.x & 63;
    const int aid = 2 * bj * (bj + 1) + bi;      // compact active-tile index

    __shared__ float    scol[TC];
    __shared__ unsigned buf[4][CAPW];
    scol[threadIdx.x] = 0.f;
    __syncthreads();

    const int c = c0 + lane * 4;
    const int rbase = r0 + wave * RPW;
    unsigned wc = 0, wflushed = 0;
    unsigned* myseg = edges + ((size_t)aid * 4 + wave) * SEG_W;
    float ca0 = 0.f, ca1 = 0.f, ca2 = 0.f, ca3 = 0.f;

#define EMIT(BB, PRED, OFF) \
    if (BB) { const unsigned p_ = __popcll(BB); \
        if (segmode && (PRED)) buf[wave][wc + mbcnt64(BB)] = etag | (OFF); \
        wc += p_; rsum += p_; }

#define FLUSHCHK \
    if (segmode && wc > (unsigned)(CAPW - 256)) { \
        for (unsigned t_ = lane; t_ < wc; t_ += 64) myseg[wflushed + t_] = buf[wave][t_]; \
        wflushed += wc; wc = 0; }

    if (r0 + TR <= c0) {
        // strictly-above-diagonal tile: no masks needed (col > row always)
        #pragma unroll 4
        for (int k = 0; k < RPW; ++k) {
            const int gr = rbase + k;
            const float4 v = *reinterpret_cast<const float4*>(g + (size_t)gr * N + c);
            FLUSHCHK
            ca0 += v.x; ca1 += v.y; ca2 += v.z; ca3 += v.w;
            const unsigned long long b0 = __ballot(v.x != 0.f);
            const unsigned long long b1 = __ballot(v.y != 0.f);
            const unsigned long long b2 = __ballot(v.z != 0.f);
            const unsigned long long b3 = __ballot(v.w != 0.f);
            unsigned rsum = 0;
            const unsigned etag = ((unsigned)gr << 16) | (unsigned)c;
            EMIT(b0, v.x != 0.f, 0u)
            EMIT(b1, v.y != 0.f, 1u)
            EMIT(b2, v.z != 0.f, 2u)
            EMIT(b3, v.w != 0.f, 3u)
            if (rsum && lane == 0) atomicAdd(&deg[gr], (float)rsum);
        }
    } else {
        // diagonal-crossing tile: per-element masks; skip fully-below rows
        int nrows = c0 + TC - rbase;
        if (nrows > RPW) nrows = RPW;
        if (nrows < 0)  nrows = 0;
        for (int k = 0; k < nrows; ++k) {
            const int gr = rbase + k;
            const float4 v = *reinterpret_cast<const float4*>(g + (size_t)gr * N + c);
            FLUSHCHK
            const bool a0 = (v.x != 0.f) && (c + 0 >= gr);
            const bool a1 = (v.y != 0.f) && (c + 1 >= gr);
            const bool a2 = (v.z != 0.f) && (c + 2 >= gr);
            const bool a3 = (v.w != 0.f) && (c + 3 >= gr);
            ca0 += (c + 0 > gr) ? v.x : 0.f;
            ca1 += (c + 1 > gr) ? v.y : 0.f;
            ca2 += (c + 2 > gr) ? v.z : 0.f;
            ca3 += (c + 3 > gr) ? v.w : 0.f;
            const unsigned long long b0 = __ballot(a0);
            const unsigned long long b1 = __ballot(a1);
            const unsigned long long b2 = __ballot(a2);
            const unsigned long long b3 = __ballot(a3);
            unsigned rsum = 0;
            const unsigned etag = ((unsigned)gr << 16) | (unsigned)c;
            EMIT(b0, a0, 0u)
            EMIT(b1, a1, 1u)
            EMIT(b2, a2, 2u)
            EMIT(b3, a3, 3u)
            if (rsum && lane == 0) atomicAdd(&deg[gr], (float)rsum);
        }
    }
#undef EMIT
#undef FLUSHCHK

    if (segmode) {
        for (unsigned t = lane; t < wc; t += 64) myseg[wflushed + t] = buf[wave][t];
        if (lane == 0) cnt[aid * 4 + wave] = wflushed + wc;
    }
    // column (strict lower counterpart) sums: LDS-combine then one flush
    if (ca0 != 0.f) atomicAdd(&scol[lane * 4 + 0], ca0);
    if (ca1 != 0.f) atomicAdd(&scol[lane * 4 + 1], ca1);
    if (ca2 != 0.f) atomicAdd(&scol[lane * 4 + 2], ca2);
    if (ca3 != 0.f) atomicAdd(&scol[lane * 4 + 3], ca3);
    __syncthreads();
    const float sv = scol[threadIdx.x];
    if (sv != 0.f) atomicAdd(&deg[c0 + threadIdx.x], sv);
}

// Fused: dense S0 (pair-balanced) + edge corrections + (never-path) fallback.
__global__ __launch_bounds__(256) void k_ll(const float* __restrict__ g,
        const float* __restrict__ deg, const float* __restrict__ params,
        const unsigned* __restrict__ cnt, const unsigned* __restrict__ edges,
        const unsigned* __restrict__ ovf, double* __restrict__ accv) {
    const int b = blockIdx.x;
    const unsigned o = *ovf;
    const float alpha = params[0], beta = params[1], sigma = params[2];
    double dlocal = 0.0;

    if (b < NDENSE) {
        if (o) return;
        const int r1 = b, r2 = N - 1 - b;       // pair rows: N+1 iters/block
        const float base1 = fmaf(alpha, deg[r1], sigma);
        const float base2 = fmaf(alpha, deg[r2], sigma);
        float local = 0.f;
        for (int j = r1 + (int)threadIdx.x; j < N; j += 256) {
            const float s = fmaf(beta, deg[j], base1);
            const float p = __fdividef(1.f, 1.f + __expf(s));
            local += __logf(1.f - p + EPS);
        }
        for (int j = r2 + (int)threadIdx.x; j < N; j += 256) {
            const float s = fmaf(beta, deg[j], base2);
            const float p = __fdividef(1.f, 1.f + __expf(s));
            local += __logf(1.f - p + EPS);
        }
        dlocal = (double)local;
    } else if (b < NDENSE + NTILES) {
        if (o) return;
        const int aid = b - NDENSE;
        float local = 0.f;
        for (int w = 0; w < 4; ++w) {
            const unsigned n = cnt[aid * 4 + w];
            const unsigned* seg = edges + ((size_t)aid * 4 + w) * SEG_W;
            for (unsigned t = threadIdx.x; t < n; t += 256) {
                const unsigned e = seg[t];
                const float di = deg[e >> 16];
                const float dj = deg[e & 0xffffu];
                const float s = fmaf(alpha, di, fmaf(beta, dj, sigma));
                const float p = __fdividef(1.f, 1.f + __expf(s));
                local += __logf(p + EPS) - __logf(1.f - p + EPS);
            }
        }
        dlocal = (double)local;
    } else {
        if (!o) return;                          // fallback only on ws overflow
        const int rb = b - NDENSE - NTILES;
        for (int q = 0; q < 8; ++q) {
            const int i = rb * 8 + q;
            const float base = fmaf(alpha, deg[i], sigma);
            float rl = 0.f;
            for (int j = i + (int)threadIdx.x; j < N; j += 256) {
                const float s = fmaf(beta, deg[j], base);
                const float p = __fdividef(1.f, 1.f + __expf(s));
                const float gv = g[(size_t)i * N + j];
                rl += (gv != 0.f) ? __logf(p + EPS) : __logf(1.f - p + EPS);
            }
            dlocal += (double)rl;
        }
    }

    #pragma unroll
    for (int off = 32; off; off >>= 1) dlocal += __shfl_xor(dlocal, off);
    __shared__ double wsum[4];
    const int wv = threadIdx.x >> 6, ln = threadIdx.x & 63;
    if (ln == 0) wsum[wv] = dlocal;
    __syncthreads();
    if (threadIdx.x == 0) {
        const double t = (wsum[0] + wsum[1]) + (wsum[2] + wsum[3]);
        if (t != 0.0) atomicAdd(&accv[(b & 63) * 8], t);   // 64 spread slots
    }
}

__global__ void k_final(const double* __restrict__ accv, float* __restrict__ out) {
    if (threadIdx.x == 0) {
        double s = 0.0;
        for (int i = 0; i < 64; ++i) s += accv[i * 8];
        out[0] = (float)(-s);
    }
}

extern "C" void kernel_launch(void* const* d_in, const int* in_sizes, int n_in,
                              void* d_out, int out_size, void* d_ws, size_t ws_size,
                              hipStream_t stream) {
    const float* params = (const float*)d_in[0];   // [alpha, beta, sigma]
    const float* graph  = (const float*)d_in[1];   // [N, N] fp32 0/1
    float* out = (float*)d_out;

    char* ws = (char*)d_ws;
    double*   accv  = (double*)(ws + OFF_ACC);
    unsigned* ovf   = (unsigned*)(ws + OFF_OVF);
    float*    deg   = (float*)(ws + OFF_DEG);
    unsigned* cnt   = (unsigned*)(ws + OFF_CNT);
    unsigned* edges = (unsigned*)(ws + OFF_EDG);
    const int segmode = (ws_size >= WS_NEED) ? 1 : 0;

    k_init<<<32, 256, 0, stream>>>(deg, accv, ovf, segmode);
    k_pass1<<<NBI * NBJ, 256, 0, stream>>>(graph, deg, cnt, edges, segmode);
    k_ll<<<NDENSE + NTILES + NFB, 256, 0, stream>>>(graph, deg, params, cnt, edges, ovf, accv);
    k_final<<<1, 64, 0, stream>>>(accv, out);
}